// Round 11
// baseline (230.514 us; speedup 1.0000x reference)
//
#include <hip/hip_runtime.h>
#include <math.h>

#define B 64
#define S 512
#define E 128
#define NT 10

// ---------------------------------------------------------------------------
// Quad rotation via DPP: lane j reads lane (j+d)&3 of its quad. 1 VALU op.
// rot1=0x39, rot2=0x4E, rot3=0x93.  (HW-verified rounds 7/9/10)
// RULE: cross-lane ops appear unconditionally under full exec; masks select
// on VALUES only.
// ---------------------------------------------------------------------------
template<int CTRL>
__device__ __forceinline__ float rotq(float x) {
    return __int_as_float(__builtin_amdgcn_mov_dpp(__float_as_int(x), CTRL, 0xF, 0xF, true));
}

__device__ __forceinline__ float frcp(float x) { return __builtin_amdgcn_rcpf(x); }

// ---------------------------------------------------------------------------
// Trans-free gate nonlinearities exploiting guaranteed ranges.
// |z| <= 1 (z is a product of cosines): sigmoid odd Taylor deg 9, err <=2.2e-6.
// ---------------------------------------------------------------------------
__device__ __forceinline__ float sig_poly(float z) {
    float s = z * z;
    float q = fmaf(2.1356922e-5f, s, -2.1081349e-4f);
    q = fmaf(q, s, 2.0833333e-3f);
    q = fmaf(q, s, -2.0833333e-2f);
    q = fmaf(q, s, 0.25f);
    return fmaf(z, q, 0.5f);
}
// tanh for |z| <= 1: Pade [3/4]  z(105+10s)/(105+45s+s^2), err <= 5.2e-6
__device__ __forceinline__ float tanh_u(float z) {
    float s = z * z;
    float n = z * fmaf(10.f, s, 105.f);
    float d = fmaf(s + 45.f, s, 105.f);
    return n * frcp(d);
}
// tanh for |x| <= 2.08 (|cx| <= sig(1)*tanh(1)/(1-sig(1)) = 2.0704, provable):
// Pade [5/6]  x(10395+1260s+21s^2)/(10395+4725s+210s^2+s^3), err <= 1e-6
__device__ __forceinline__ float tanh_c(float x) {
    float s = x * x;
    float n = x * fmaf(s, fmaf(21.f, s, 1260.f), 10395.f);
    float d = fmaf(s, fmaf(s, s + 210.f, 4725.f), 10395.f);
    return n * frcp(d);
}

// ---------------------------------------------------------------------------
// k1: 16 positions/block; emb rows staged once into LDS via coalesced float4
// loads; conflict-free reads (HW-verified rounds 8-10).
// ---------------------------------------------------------------------------
__global__ void __launch_bounds__(256) k1_xproj(
        const int* __restrict__ x, const float* __restrict__ emb,
        const float* __restrict__ Wf, const float* __restrict__ bf, const float* __restrict__ thf,
        const float* __restrict__ Wi, const float* __restrict__ bi, const float* __restrict__ thi,
        const float* __restrict__ Wu, const float* __restrict__ bu, const float* __restrict__ thu,
        const float* __restrict__ Wo, const float* __restrict__ bo, const float* __restrict__ tho,
        float* __restrict__ Xproj) {
    __shared__ __align__(16) float Wl[16][132];
    __shared__ __align__(16) float rows[16][132];
    __shared__ float bl[16];
    const int tid = threadIdx.x;
    {
        const float* Wm[4] = {Wf, Wi, Wu, Wo};
        for (int idx = tid; idx < 16 * E; idx += 256) {
            int e = idx >> 4, q = idx & 15;
            int g = q & 3, j = q >> 2;
            Wl[q][e] = Wm[g][e * 4 + j];
        }
        if (tid < 16) {
            const float* bm[4] = {bf, bi, bu, bo};
            const float* tm[4] = {thf, thi, thu, tho};
            int g = tid & 3, j = tid >> 2;
            bl[tid] = bm[g][j] + tm[g][j];
        }
    }
    const int p0 = blockIdx.x * 16;
    #pragma unroll
    for (int k = 0; k < 2; ++k) {
        int i4 = k * 256 + tid;              // float4 unit: 16 rows x 32
        int r  = i4 >> 5;
        int e4 = i4 & 31;
        const float4* rp = (const float4*)(emb + (size_t)x[p0 + r] * E);
        *(float4*)(&rows[r][e4 * 4]) = rp[e4];
    }
    __syncthreads();
    const int pl = tid >> 4, q = tid & 15;
    float acc = bl[q];
    #pragma unroll
    for (int e = 0; e < E; e += 4) {
        float4 wv = *(const float4*)(&Wl[q][e]);
        float4 rv = *(const float4*)(&rows[pl][e]);
        acc += rv.x * wv.x + rv.y * wv.y + rv.z * wv.z + rv.w * wv.w;
    }
    Xproj[(size_t)(p0 + pl) * 16 + q] = acc;
}

// ---------------------------------------------------------------------------
// k2: sequential LSTM recurrence; round-10 structure (P=8 pipelined prefetch,
// DPP rotations) with exp/rcp gate chains replaced by FMA polys/Pades.
// Trans ops/step: 14 -> 6 (4 cos + 2 rcp); dependent chain mostly full-rate.
//   Z0=c1c2c3, Z1=c0c1, Z2=c0c1c2, Z3=c0c1c2c3  (HW-verified rounds 2..10)
// hbuf layout: [B][S][4] (f32)
// ---------------------------------------------------------------------------
__global__ void __launch_bounds__(64) k2_recur(
        const float* __restrict__ Xproj,
        const float* __restrict__ Wf, const float* __restrict__ Wi,
        const float* __restrict__ Wu, const float* __restrict__ Wo,
        float* __restrict__ hbuf) {
    const int lane = threadIdx.x;
    const int T = blockIdx.x * 64 + lane;
    const int b = T >> 2, j = T & 3;

    // recurrent weights pre-permuted: hx slot d holds hx_{(j+d)&3}
    const float* Wm[4] = {Wf, Wi, Wu, Wo};
    float w[4][4];
    #pragma unroll
    for (int g = 0; g < 4; ++g)
        #pragma unroll
        for (int d = 0; d < 4; ++d)
            w[g][d] = Wm[g][(E + ((j + d) & 3)) * 4 + j];

    const bool m_own = (j != 0);
    const bool m_r1  = (j == 0) || (j == 3);
    const bool m_r2  = (j != 1);

    float hx0 = 0.f, hx1 = 0.f, hx2 = 0.f, hx3 = 0.f, cx = 0.f;

    const float4* xp4 = (const float4*)Xproj + (size_t)b * S * 4 + j;
    float* hout = hbuf + (size_t)b * S * 4 + j;

    constexpr int P = 8;                      // S % P == 0
    float4 cur[P], nxt[P];
    #pragma unroll
    for (int p = 0; p < P; ++p) cur[p] = xp4[(size_t)p * 4];

    for (int tb = 0; tb < S; tb += P) {
        // issue next block's loads immediately (8 in flight, used ~2000 cyc later)
        #pragma unroll
        for (int p = 0; p < P; ++p) {
            int tt = tb + P + p; if (tt >= S) tt = S - 1;   // clamped tail prefetch
            nxt[p] = xp4[(size_t)tt * 4];
        }
        #pragma unroll
        for (int p = 0; p < P; ++p) {
            const float4 xp = cur[p];
            const int t = tb + p;

            float pre0 = fmaf(w[0][0], hx0, xp.x) + fmaf(w[0][1], hx1, w[0][2]*hx2 + w[0][3]*hx3);
            float pre1 = fmaf(w[1][0], hx0, xp.y) + fmaf(w[1][1], hx1, w[1][2]*hx2 + w[1][3]*hx3);
            float pre2 = fmaf(w[2][0], hx0, xp.z) + fmaf(w[2][1], hx1, w[2][2]*hx2 + w[2][3]*hx3);
            float pre3 = fmaf(w[3][0], hx0, xp.w) + fmaf(w[3][1], hx1, w[3][2]*hx2 + w[3][3]*hx3);

            float c0 = __cosf(pre0);
            float c1 = __cosf(pre1);
            float c2 = __cosf(pre2);
            float c3 = __cosf(pre3);

            float a01 = rotq<0x39>(c0), a02 = rotq<0x4E>(c0), a03 = rotq<0x93>(c0);
            float a11 = rotq<0x39>(c1), a12 = rotq<0x4E>(c1), a13 = rotq<0x93>(c1);
            float a21 = rotq<0x39>(c2), a22 = rotq<0x4E>(c2), a23 = rotq<0x93>(c2);
            float a31 = rotq<0x39>(c3), a32 = rotq<0x4E>(c3), a33 = rotq<0x93>(c3);

            float z0 = ((m_own ? c0 : 1.f) * (m_r1 ? a01 : 1.f)) * ((m_r2 ? a02 : 1.f) * a03);
            float z1 = ((m_own ? c1 : 1.f) * (m_r1 ? a11 : 1.f)) * ((m_r2 ? a12 : 1.f) * a13);
            float z2 = ((m_own ? c2 : 1.f) * (m_r1 ? a21 : 1.f)) * ((m_r2 ? a22 : 1.f) * a23);
            float z3 = ((m_own ? c3 : 1.f) * (m_r1 ? a31 : 1.f)) * ((m_r2 ? a32 : 1.f) * a33);

            float f  = sig_poly(z0);
            float i_ = sig_poly(z1);
            float u  = tanh_u(z2);
            float o  = sig_poly(z3);

            cx = fmaf(f, cx, i_ * u);
            float h = o * tanh_c(cx);

            hout[(size_t)t * 4] = h;

            float h1 = rotq<0x39>(h), h2 = rotq<0x4E>(h), h3 = rotq<0x93>(h);
            hx0 = h; hx1 = h1; hx2 = h2; hx3 = h3;
        }
        #pragma unroll
        for (int p = 0; p < P; ++p) cur[p] = nxt[p];
    }
}

// ---------------------------------------------------------------------------
// k3: logits = h @ Wt + bt, log_softmax over 10 tags (verified rounds 7-10).
// ---------------------------------------------------------------------------
__global__ void __launch_bounds__(256) k3_head(
        const float* __restrict__ hbuf, const float* __restrict__ Wt,
        const float* __restrict__ bt, float* __restrict__ out) {
    const int pos = blockIdx.x * 256 + threadIdx.x;
    if (pos >= B * S) return;
    float4 h = ((const float4*)hbuf)[pos];
    float lo[NT];
    float m = -1e30f;
    #pragma unroll
    for (int t = 0; t < NT; ++t) {
        lo[t] = bt[t] + h.x * Wt[t] + h.y * Wt[NT + t] + h.z * Wt[2 * NT + t] + h.w * Wt[3 * NT + t];
        m = fmaxf(m, lo[t]);
    }
    float sum = 0.f;
    #pragma unroll
    for (int t = 0; t < NT; ++t) sum += __expf(lo[t] - m);
    float lse = m + __logf(sum);
    float* op = out + (size_t)pos * NT;
    #pragma unroll
    for (int t = 0; t < NT; ++t) op[t] = lo[t] - lse;
}

extern "C" void kernel_launch(void* const* d_in, const int* in_sizes, int n_in,
                              void* d_out, int out_size, void* d_ws, size_t ws_size,
                              hipStream_t stream) {
    const int*   x   = (const int*)d_in[0];
    const float* emb = (const float*)d_in[1];
    const float* Wf  = (const float*)d_in[2];
    const float* bf  = (const float*)d_in[3];
    const float* thf = (const float*)d_in[4];
    const float* Wi  = (const float*)d_in[5];
    const float* bi  = (const float*)d_in[6];
    const float* thi = (const float*)d_in[7];
    const float* Wu  = (const float*)d_in[8];
    const float* bu  = (const float*)d_in[9];
    const float* thu = (const float*)d_in[10];
    const float* Wo  = (const float*)d_in[11];
    const float* bo  = (const float*)d_in[12];
    const float* tho = (const float*)d_in[13];
    const float* Wt  = (const float*)d_in[14];
    const float* bt  = (const float*)d_in[15];
    float* out = (float*)d_out;

    // workspace: Xproj [B*S*16] f32, then hbuf [B*S*4] f32
    if (ws_size < (size_t)(B * S * 20) * sizeof(float)) return;
    float* Xproj = (float*)d_ws;
    float* hbuf  = Xproj + (size_t)B * S * 16;

    k1_xproj<<<(B * S) / 16, 256, 0, stream>>>(x, emb, Wf, bf, thf, Wi, bi, thi,
                                               Wu, bu, thu, Wo, bo, tho, Xproj);
    k2_recur<<<4, 64, 0, stream>>>(Xproj, Wf, Wi, Wu, Wo, hbuf);
    k3_head<<<(B * S) / 256, 256, 0, stream>>>(hbuf, Wt, bt, out);
}

// Round 12
// 193.747 us; speedup vs baseline: 1.1898x; 1.1898x over previous
//
#include <hip/hip_runtime.h>
#include <math.h>

#define B 64
#define S 512
#define E 128
#define NT 10

// ---------------------------------------------------------------------------
// Quad rotation via DPP: lane j reads lane (j+d)&3 of its quad. 1 VALU op.
// rot1=0x39, rot2=0x4E, rot3=0x93.  (HW-verified rounds 7/9/10/11)
// Row rotation (16-lane rows): ror4=0x124, ror8=0x128 — used ONLY inside
// commutative butterfly products, so rotation direction is irrelevant.
// RULE: cross-lane ops appear unconditionally under full exec; masks select
// on VALUES only. Loop body below has zero control flow.
// ---------------------------------------------------------------------------
template<int CTRL>
__device__ __forceinline__ float rotq(float x) {
    return __int_as_float(__builtin_amdgcn_mov_dpp(__float_as_int(x), CTRL, 0xF, 0xF, true));
}

__device__ __forceinline__ float frcp(float x) { return __builtin_amdgcn_rcpf(x); }

// sigmoid for |z| <= 1 (z = product of cosines): odd Taylor deg 9, err <=2.2e-6
__device__ __forceinline__ float sig_poly(float z) {
    float s = z * z;
    float q = fmaf(2.1356922e-5f, s, -2.1081349e-4f);
    q = fmaf(q, s, 2.0833333e-3f);
    q = fmaf(q, s, -2.0833333e-2f);
    q = fmaf(q, s, 0.25f);
    return fmaf(z, q, 0.5f);
}
// tanh for |z| <= 1: Pade [3/4]  z(105+10s)/(105+45s+s^2), err <= 5.2e-6
__device__ __forceinline__ float tanh_u(float z) {
    float s = z * z;
    float n = z * fmaf(10.f, s, 105.f);
    float d = fmaf(s + 45.f, s, 105.f);
    return n * frcp(d);
}
// tanh for |x| <= 2.08 (|cx| <= sig(1)*tanh(1)/(1-sig(1)) = 2.0704, provable):
// Pade [5/6], err <= 1e-6
__device__ __forceinline__ float tanh_c(float x) {
    float s = x * x;
    float n = x * fmaf(s, fmaf(21.f, s, 1260.f), 10395.f);
    float d = fmaf(s, fmaf(s, s + 210.f, 4725.f), 10395.f);
    return n * frcp(d);
}

// ---------------------------------------------------------------------------
// k1: 16 positions/block; emb rows staged once into LDS via coalesced float4
// loads; conflict-free reads (HW-verified rounds 8-11). VERBATIM.
// ---------------------------------------------------------------------------
__global__ void __launch_bounds__(256) k1_xproj(
        const int* __restrict__ x, const float* __restrict__ emb,
        const float* __restrict__ Wf, const float* __restrict__ bf, const float* __restrict__ thf,
        const float* __restrict__ Wi, const float* __restrict__ bi, const float* __restrict__ thi,
        const float* __restrict__ Wu, const float* __restrict__ bu, const float* __restrict__ thu,
        const float* __restrict__ Wo, const float* __restrict__ bo, const float* __restrict__ tho,
        float* __restrict__ Xproj) {
    __shared__ __align__(16) float Wl[16][132];
    __shared__ __align__(16) float rows[16][132];
    __shared__ float bl[16];
    const int tid = threadIdx.x;
    {
        const float* Wm[4] = {Wf, Wi, Wu, Wo};
        for (int idx = tid; idx < 16 * E; idx += 256) {
            int e = idx >> 4, q = idx & 15;
            int g = q & 3, j = q >> 2;
            Wl[q][e] = Wm[g][e * 4 + j];
        }
        if (tid < 16) {
            const float* bm[4] = {bf, bi, bu, bo};
            const float* tm[4] = {thf, thi, thu, tho};
            int g = tid & 3, j = tid >> 2;
            bl[tid] = bm[g][j] + tm[g][j];
        }
    }
    const int p0 = blockIdx.x * 16;
    #pragma unroll
    for (int k = 0; k < 2; ++k) {
        int i4 = k * 256 + tid;              // float4 unit: 16 rows x 32
        int r  = i4 >> 5;
        int e4 = i4 & 31;
        const float4* rp = (const float4*)(emb + (size_t)x[p0 + r] * E);
        *(float4*)(&rows[r][e4 * 4]) = rp[e4];
    }
    __syncthreads();
    const int pl = tid >> 4, q = tid & 15;
    float acc = bl[q];
    #pragma unroll
    for (int e = 0; e < E; e += 4) {
        float4 wv = *(const float4*)(&Wl[q][e]);
        float4 rv = *(const float4*)(&rows[pl][e]);
        acc += rv.x * wv.x + rv.y * wv.y + rv.z * wv.z + rv.w * wv.w;
    }
    Xproj[(size_t)(p0 + pl) * 16 + q] = acc;
}

// ---------------------------------------------------------------------------
// k2 v3: 16 lanes per batch element — lane l = g*4 + j (gate g, wire j).
// 16 blocks x 64 lanes = 1024 lanes = B x 16.  Wires live in QUADS (all
// quad_perm semantics HW-verified); gates live at stride 4 within 16-lane
// rows, combined ONLY via direction-agnostic butterfly products.
// Per-step per-lane: 1 pre, 1 cos, 1 z, 1 gate poly (~60 instr vs 120).
//   Z0=c1c2c3, Z1=c0c1, Z2=c0c1c2, Z3=c0c1c2c3  (HW-verified rounds 2..11)
// P=8 pipelined scalar prefetch (round-10 structure). hbuf: [B][S][4] f32.
// ---------------------------------------------------------------------------
__global__ void __launch_bounds__(64) k2_recur(
        const float* __restrict__ Xproj,
        const float* __restrict__ Wf, const float* __restrict__ Wi,
        const float* __restrict__ Wu, const float* __restrict__ Wo,
        float* __restrict__ hbuf) {
    const int lane = threadIdx.x;
    const int gl = blockIdx.x * 64 + lane;
    const int b = gl >> 4;                 // batch element
    const int l16 = lane & 15;
    const int g = l16 >> 2, j = l16 & 3;   // gate, wire

    // per-lane gate weight row, pre-permuted: hx slot d holds hx_{(j+d)&3}
    const float* Wg = (g == 0) ? Wf : (g == 1) ? Wi : (g == 2) ? Wu : Wo;
    const float w0 = Wg[(E + ((j + 0) & 3)) * 4 + j];
    const float w1 = Wg[(E + ((j + 1) & 3)) * 4 + j];
    const float w2 = Wg[(E + ((j + 2) & 3)) * 4 + j];
    const float w3 = Wg[(E + ((j + 3) & 3)) * 4 + j];

    // z-product inclusion masks (depend on wire j only; HW-verified)
    const bool m_own = (j != 0);
    const bool m_r1  = (j == 0) || (j == 3);
    const bool m_r2  = (j != 1);
    // gate-combine masks (depend on gate g only)
    const bool is_u  = (g == 2);
    const bool is_f  = (g == 0);
    const bool is_iu = (g == 1) || (g == 2);
    const bool is_o  = (g == 3);

    float hx0 = 0.f, hx1 = 0.f, hx2 = 0.f, hx3 = 0.f, cx = 0.f;

    const float* xp = Xproj + (size_t)b * S * 16 + (j * 4 + g);
    float* hout = hbuf + ((size_t)b * S) * 4 + j;   // all 4 g-lanes write same value

    constexpr int P = 8;                   // S % P == 0
    float cur[P], nxt[P];
    #pragma unroll
    for (int p = 0; p < P; ++p) cur[p] = xp[(size_t)p * 16];

    for (int tb = 0; tb < S; tb += P) {
        #pragma unroll
        for (int p = 0; p < P; ++p) {
            int tt = tb + P + p; if (tt >= S) tt = S - 1;   // clamped tail prefetch
            nxt[p] = xp[(size_t)tt * 16];
        }
        #pragma unroll
        for (int p = 0; p < P; ++p) {
            const int t = tb + p;

            float pre = fmaf(w0, hx0, cur[p]) + fmaf(w1, hx1, fmaf(w2, hx2, w3 * hx3));
            float c = __cosf(pre);

            // z-product across wires (quads, verified)
            float a1 = rotq<0x39>(c), a2 = rotq<0x4E>(c), a3 = rotq<0x93>(c);
            float z = ((m_own ? c : 1.f) * (m_r1 ? a1 : 1.f)) * ((m_r2 ? a2 : 1.f) * a3);

            // gate nonlinearity: compute both, select by gate (values only)
            float ys = sig_poly(z);
            float yt = tanh_u(z);
            float y  = is_u ? yt : ys;

            // combine across gates: direction-agnostic butterfly products
            float ef  = is_f  ? y : 1.f;    // -> product = f
            float eiu = is_iu ? y : 1.f;    // -> product = i*u
            float eo  = is_o  ? y : 1.f;    // -> product = o
            float pf  = ef  * rotq<0x128>(ef);   pf  = pf  * rotq<0x124>(pf);
            float piu = eiu * rotq<0x128>(eiu);  piu = piu * rotq<0x124>(piu);
            float po  = eo  * rotq<0x128>(eo);   po  = po  * rotq<0x124>(po);

            cx = fmaf(pf, cx, piu);
            float h = po * tanh_c(cx);

            hout[(size_t)t * 4] = h;        // 4 g-redundant writers, same value

            hx0 = h;
            hx1 = rotq<0x39>(h); hx2 = rotq<0x4E>(h); hx3 = rotq<0x93>(h);
        }
        #pragma unroll
        for (int p = 0; p < P; ++p) cur[p] = nxt[p];
    }
}

// ---------------------------------------------------------------------------
// k3: logits = h @ Wt + bt, log_softmax over 10 tags (verified rounds 7-11).
// ---------------------------------------------------------------------------
__global__ void __launch_bounds__(256) k3_head(
        const float* __restrict__ hbuf, const float* __restrict__ Wt,
        const float* __restrict__ bt, float* __restrict__ out) {
    const int pos = blockIdx.x * 256 + threadIdx.x;
    if (pos >= B * S) return;
    float4 h = ((const float4*)hbuf)[pos];
    float lo[NT];
    float m = -1e30f;
    #pragma unroll
    for (int t = 0; t < NT; ++t) {
        lo[t] = bt[t] + h.x * Wt[t] + h.y * Wt[NT + t] + h.z * Wt[2 * NT + t] + h.w * Wt[3 * NT + t];
        m = fmaxf(m, lo[t]);
    }
    float sum = 0.f;
    #pragma unroll
    for (int t = 0; t < NT; ++t) sum += __expf(lo[t] - m);
    float lse = m + __logf(sum);
    float* op = out + (size_t)pos * NT;
    #pragma unroll
    for (int t = 0; t < NT; ++t) op[t] = lo[t] - lse;
}

extern "C" void kernel_launch(void* const* d_in, const int* in_sizes, int n_in,
                              void* d_out, int out_size, void* d_ws, size_t ws_size,
                              hipStream_t stream) {
    const int*   x   = (const int*)d_in[0];
    const float* emb = (const float*)d_in[1];
    const float* Wf  = (const float*)d_in[2];
    const float* bf  = (const float*)d_in[3];
    const float* thf = (const float*)d_in[4];
    const float* Wi  = (const float*)d_in[5];
    const float* bi  = (const float*)d_in[6];
    const float* thi = (const float*)d_in[7];
    const float* Wu  = (const float*)d_in[8];
    const float* bu  = (const float*)d_in[9];
    const float* thu = (const float*)d_in[10];
    const float* Wo  = (const float*)d_in[11];
    const float* bo  = (const float*)d_in[12];
    const float* tho = (const float*)d_in[13];
    const float* Wt  = (const float*)d_in[14];
    const float* bt  = (const float*)d_in[15];
    float* out = (float*)d_out;

    // workspace: Xproj [B*S*16] f32, then hbuf [B*S*4] f32
    if (ws_size < (size_t)(B * S * 20) * sizeof(float)) return;
    float* Xproj = (float*)d_ws;
    float* hbuf  = Xproj + (size_t)B * S * 16;

    k1_xproj<<<(B * S) / 16, 256, 0, stream>>>(x, emb, Wf, bf, thf, Wi, bi, thi,
                                               Wu, bu, thu, Wo, bo, tho, Xproj);
    k2_recur<<<16, 64, 0, stream>>>(Xproj, Wf, Wi, Wu, Wo, hbuf);
    k3_head<<<(B * S) / 256, 256, 0, stream>>>(hbuf, Wt, bt, out);
}

// Round 13
// 185.415 us; speedup vs baseline: 1.2432x; 1.0449x over previous
//
#include <hip/hip_runtime.h>
#include <math.h>

#define B 64
#define S 512
#define E 128
#define NT 10

// ---------------------------------------------------------------------------
// Quad rotation via DPP: lane j reads lane (j+d)&3 of its quad. 1 VALU op.
// rot1=0x39, rot2=0x4E, rot3=0x93.  (HW-verified rounds 7/9/10/11/12)
// Row rotation (16-lane rows): ror4=0x124, ror8=0x128 — used ONLY inside
// commutative butterfly products (direction-agnostic; HW-verified round 12).
// RULE: cross-lane ops appear unconditionally under full exec; masks select
// on VALUES only. Loop body below has zero control flow.
// ---------------------------------------------------------------------------
template<int CTRL>
__device__ __forceinline__ float rotq(float x) {
    return __int_as_float(__builtin_amdgcn_mov_dpp(__float_as_int(x), CTRL, 0xF, 0xF, true));
}

__device__ __forceinline__ float frcp(float x) { return __builtin_amdgcn_rcpf(x); }

// tanh for |x| <= 2.08 (|cx| <= sig(1)*tanh(1)/(1-sig(1)) = 2.0704, provable):
// Pade [5/6], err <= 1e-6  (HW-verified rounds 11/12)
__device__ __forceinline__ float tanh_c(float x) {
    float s = x * x;
    float n = x * fmaf(s, fmaf(21.f, s, 1260.f), 10395.f);
    float d = fmaf(s, fmaf(s, s + 210.f, 4725.f), 10395.f);
    return n * frcp(d);
}

#define INV2PI 0.15915494309189535f

// ---------------------------------------------------------------------------
// k1: 16 positions/block; emb rows staged once into LDS (HW-verified rounds
// 8-12). CHANGE: Wl and bl pre-scaled by 1/2pi so Xproj is in REVOLUTIONS —
// k2 then feeds raw v_cos_f32 (ISA: cos(S0*2pi)) with no per-step scale mul.
// ---------------------------------------------------------------------------
__global__ void __launch_bounds__(256) k1_xproj(
        const int* __restrict__ x, const float* __restrict__ emb,
        const float* __restrict__ Wf, const float* __restrict__ bf, const float* __restrict__ thf,
        const float* __restrict__ Wi, const float* __restrict__ bi, const float* __restrict__ thi,
        const float* __restrict__ Wu, const float* __restrict__ bu, const float* __restrict__ thu,
        const float* __restrict__ Wo, const float* __restrict__ bo, const float* __restrict__ tho,
        float* __restrict__ Xproj) {
    __shared__ __align__(16) float Wl[16][132];
    __shared__ __align__(16) float rows[16][132];
    __shared__ float bl[16];
    const int tid = threadIdx.x;
    {
        const float* Wm[4] = {Wf, Wi, Wu, Wo};
        for (int idx = tid; idx < 16 * E; idx += 256) {
            int e = idx >> 4, q = idx & 15;
            int g = q & 3, j = q >> 2;
            Wl[q][e] = Wm[g][e * 4 + j] * INV2PI;
        }
        if (tid < 16) {
            const float* bm[4] = {bf, bi, bu, bo};
            const float* tm[4] = {thf, thi, thu, tho};
            int g = tid & 3, j = tid >> 2;
            bl[tid] = (bm[g][j] + tm[g][j]) * INV2PI;
        }
    }
    const int p0 = blockIdx.x * 16;
    #pragma unroll
    for (int k = 0; k < 2; ++k) {
        int i4 = k * 256 + tid;              // float4 unit: 16 rows x 32
        int r  = i4 >> 5;
        int e4 = i4 & 31;
        const float4* rp = (const float4*)(emb + (size_t)x[p0 + r] * E);
        *(float4*)(&rows[r][e4 * 4]) = rp[e4];
    }
    __syncthreads();
    const int pl = tid >> 4, q = tid & 15;
    float acc = bl[q];
    #pragma unroll
    for (int e = 0; e < E; e += 4) {
        float4 wv = *(const float4*)(&Wl[q][e]);
        float4 rv = *(const float4*)(&rows[pl][e]);
        acc += rv.x * wv.x + rv.y * wv.y + rv.z * wv.z + rv.w * wv.w;
    }
    Xproj[(size_t)(p0 + pl) * 16 + q] = acc;
}

// ---------------------------------------------------------------------------
// k2 v4: 16 lanes per batch element, lane l = g*4 + j (round-12 layout,
// HW-verified). Chain cuts this round:
//  - unified per-lane rational gate  y = b0 + z*(n0+n1*s)/(d0+d1*s+d2*s^2)
//    (u-lane: tanh Pade[3/4]; others: sigma(z) = 0.5 + 0.5*tanh(z/2), exact
//    transform of the same Pade) — no dual computation, no select.
//  - Xproj/w pre-scaled to revolutions -> raw v_cos_f32, no scale mul.
//   Z0=c1c2c3, Z1=c0c1, Z2=c0c1c2, Z3=c0c1c2c3  (HW-verified rounds 2..12)
// P=8 pipelined scalar prefetch. hbuf: [B][S][4] f32.
// ---------------------------------------------------------------------------
__global__ void __launch_bounds__(64) k2_recur(
        const float* __restrict__ Xproj,
        const float* __restrict__ Wf, const float* __restrict__ Wi,
        const float* __restrict__ Wu, const float* __restrict__ Wo,
        float* __restrict__ hbuf) {
    const int lane = threadIdx.x;
    const int gl = blockIdx.x * 64 + lane;
    const int b = gl >> 4;                 // batch element
    const int l16 = lane & 15;
    const int g = l16 >> 2, j = l16 & 3;   // gate, wire

    // per-lane gate weight row (scaled to revolutions), pre-permuted:
    // hx slot d holds hx_{(j+d)&3}
    const float* Wg = (g == 0) ? Wf : (g == 1) ? Wi : (g == 2) ? Wu : Wo;
    const float w0 = Wg[(E + ((j + 0) & 3)) * 4 + j] * INV2PI;
    const float w1 = Wg[(E + ((j + 1) & 3)) * 4 + j] * INV2PI;
    const float w2 = Wg[(E + ((j + 2) & 3)) * 4 + j] * INV2PI;
    const float w3 = Wg[(E + ((j + 3) & 3)) * 4 + j] * INV2PI;

    // z-product inclusion masks (wire j; HW-verified)
    const bool m_own = (j != 0);
    const bool m_r1  = (j == 0) || (j == 3);
    const bool m_r2  = (j != 1);
    // gate-combine masks (gate g; HW-verified round 12)
    const bool is_u  = (g == 2);
    const bool is_f  = (g == 0);
    const bool is_iu = (g == 1) || (g == 2);
    const bool is_o  = (g == 3);

    // unified rational-gate constants (per-lane, set once)
    const float b0 = is_u ? 0.f   : 0.5f;
    const float n0 = is_u ? 105.f : 26.25f;
    const float n1 = is_u ? 10.f  : 0.625f;
    const float d1 = is_u ? 45.f  : 11.25f;
    const float d2 = is_u ? 1.f   : 0.0625f;

    float hx0 = 0.f, hx1 = 0.f, hx2 = 0.f, hx3 = 0.f, cx = 0.f;

    const float* xp = Xproj + (size_t)b * S * 16 + (j * 4 + g);
    float* hout = hbuf + ((size_t)b * S) * 4 + j;   // 4 g-lanes write same value

    constexpr int P = 8;                   // S % P == 0
    float cur[P], nxt[P];
    #pragma unroll
    for (int p = 0; p < P; ++p) cur[p] = xp[(size_t)p * 16];

    for (int tb = 0; tb < S; tb += P) {
        #pragma unroll
        for (int p = 0; p < P; ++p) {
            int tt = tb + P + p; if (tt >= S) tt = S - 1;   // clamped tail prefetch
            nxt[p] = xp[(size_t)tt * 16];
        }
        #pragma unroll
        for (int p = 0; p < P; ++p) {
            const int t = tb + p;

            // balanced pre tree (depth 4 from h); everything in revolutions
            float t1 = fmaf(w1, hx1, fmaf(w0, hx0, cur[p]));
            float t2 = fmaf(w3, hx3, w2 * hx2);
            float pre = t1 + t2;

            float c = __builtin_amdgcn_cosf(pre);   // v_cos_f32: cos(2*pi*pre)

            // z-product across wires (quads, verified)
            float a1 = rotq<0x39>(c), a2 = rotq<0x4E>(c), a3 = rotq<0x93>(c);
            float z = ((m_own ? c : 1.f) * (m_r1 ? a1 : 1.f)) * ((m_r2 ? a2 : 1.f) * a3);

            // unified rational gate
            float s = z * z;
            float num = z * fmaf(n1, s, n0);
            float den = fmaf(fmaf(d2, s, d1), s, 105.f);
            float y = fmaf(num, frcp(den), b0);

            // combine across gates: direction-agnostic butterfly products
            float ef  = is_f  ? y : 1.f;    // -> product over g-lanes = f
            float eiu = is_iu ? y : 1.f;    // -> i*u
            float eo  = is_o  ? y : 1.f;    // -> o
            float pf  = ef  * rotq<0x128>(ef);   pf  = pf  * rotq<0x124>(pf);
            float piu = eiu * rotq<0x128>(eiu);  piu = piu * rotq<0x124>(piu);
            float po  = eo  * rotq<0x128>(eo);   po  = po  * rotq<0x124>(po);

            cx = fmaf(pf, cx, piu);
            float h = po * tanh_c(cx);

            hout[(size_t)t * 4] = h;        // 4 g-redundant writers, same value

            hx0 = h;
            hx1 = rotq<0x39>(h); hx2 = rotq<0x4E>(h); hx3 = rotq<0x93>(h);
        }
        #pragma unroll
        for (int p = 0; p < P; ++p) cur[p] = nxt[p];
    }
}

// ---------------------------------------------------------------------------
// k3: logits = h @ Wt + bt, log_softmax over 10 tags (verified rounds 7-12).
// ---------------------------------------------------------------------------
__global__ void __launch_bounds__(256) k3_head(
        const float* __restrict__ hbuf, const float* __restrict__ Wt,
        const float* __restrict__ bt, float* __restrict__ out) {
    const int pos = blockIdx.x * 256 + threadIdx.x;
    if (pos >= B * S) return;
    float4 h = ((const float4*)hbuf)[pos];
    float lo[NT];
    float m = -1e30f;
    #pragma unroll
    for (int t = 0; t < NT; ++t) {
        lo[t] = bt[t] + h.x * Wt[t] + h.y * Wt[NT + t] + h.z * Wt[2 * NT + t] + h.w * Wt[3 * NT + t];
        m = fmaxf(m, lo[t]);
    }
    float sum = 0.f;
    #pragma unroll
    for (int t = 0; t < NT; ++t) sum += __expf(lo[t] - m);
    float lse = m + __logf(sum);
    float* op = out + (size_t)pos * NT;
    #pragma unroll
    for (int t = 0; t < NT; ++t) op[t] = lo[t] - lse;
}

extern "C" void kernel_launch(void* const* d_in, const int* in_sizes, int n_in,
                              void* d_out, int out_size, void* d_ws, size_t ws_size,
                              hipStream_t stream) {
    const int*   x   = (const int*)d_in[0];
    const float* emb = (const float*)d_in[1];
    const float* Wf  = (const float*)d_in[2];
    const float* bf  = (const float*)d_in[3];
    const float* thf = (const float*)d_in[4];
    const float* Wi  = (const float*)d_in[5];
    const float* bi  = (const float*)d_in[6];
    const float* thi = (const float*)d_in[7];
    const float* Wu  = (const float*)d_in[8];
    const float* bu  = (const float*)d_in[9];
    const float* thu = (const float*)d_in[10];
    const float* Wo  = (const float*)d_in[11];
    const float* bo  = (const float*)d_in[12];
    const float* tho = (const float*)d_in[13];
    const float* Wt  = (const float*)d_in[14];
    const float* bt  = (const float*)d_in[15];
    float* out = (float*)d_out;

    // workspace: Xproj [B*S*16] f32, then hbuf [B*S*4] f32
    if (ws_size < (size_t)(B * S * 20) * sizeof(float)) return;
    float* Xproj = (float*)d_ws;
    float* hbuf  = Xproj + (size_t)B * S * 16;

    k1_xproj<<<(B * S) / 16, 256, 0, stream>>>(x, emb, Wf, bf, thf, Wi, bi, thi,
                                               Wu, bu, thu, Wo, bo, tho, Xproj);
    k2_recur<<<16, 64, 0, stream>>>(Xproj, Wf, Wi, Wu, Wo, hbuf);
    k3_head<<<(B * S) / 256, 256, 0, stream>>>(hbuf, Wt, bt, out);
}

// Round 14
// 144.339 us; speedup vs baseline: 1.5970x; 1.2846x over previous
//
#include <hip/hip_runtime.h>
#include <math.h>

#define B 64
#define S 512
#define E 128
#define NT 10
#define CHUNK_L 32      // stored steps per chunk
#define WARM 128        // speculative warm-up steps (state decays <=0.83^128)
#define NCHUNK (S / CHUNK_L)

// ---------------------------------------------------------------------------
// Quad rotation via DPP: lane j reads lane (j+d)&3 of its quad. 1 VALU op.
// rot1=0x39, rot2=0x4E, rot3=0x93.  (HW-verified rounds 7-13)
// Row rotation (16-lane rows): ror4=0x124, ror8=0x128 — only inside
// commutative butterfly products (direction-agnostic; HW-verified r12/13).
// RULE: cross-lane ops appear unconditionally under full exec; masks select
// on VALUES only. The only control flow in the loop is WAVE-UNIFORM
// (chunk-uniform t bounds / store predicate) and contains no cross-lane ops.
// ---------------------------------------------------------------------------
template<int CTRL>
__device__ __forceinline__ float rotq(float x) {
    return __int_as_float(__builtin_amdgcn_mov_dpp(__float_as_int(x), CTRL, 0xF, 0xF, true));
}

__device__ __forceinline__ float frcp(float x) { return __builtin_amdgcn_rcpf(x); }

// tanh for |x| <= 2.08 (|cx| <= sig(1)*tanh(1)/(1-sig(1)) = 2.0704, provable):
// Pade [5/6], err <= 1e-6  (HW-verified rounds 11-13)
__device__ __forceinline__ float tanh_c(float x) {
    float s = x * x;
    float n = x * fmaf(s, fmaf(21.f, s, 1260.f), 10395.f);
    float d = fmaf(s, fmaf(s, s + 210.f, 4725.f), 10395.f);
    return n * frcp(d);
}

#define INV2PI 0.15915494309189535f

// ---------------------------------------------------------------------------
// k1: 16 positions/block; emb rows staged once into LDS (HW-verified r8-13).
// Wl/bl pre-scaled by 1/2pi -> Xproj in revolutions for raw v_cos_f32.
// ---------------------------------------------------------------------------
__global__ void __launch_bounds__(256) k1_xproj(
        const int* __restrict__ x, const float* __restrict__ emb,
        const float* __restrict__ Wf, const float* __restrict__ bf, const float* __restrict__ thf,
        const float* __restrict__ Wi, const float* __restrict__ bi, const float* __restrict__ thi,
        const float* __restrict__ Wu, const float* __restrict__ bu, const float* __restrict__ thu,
        const float* __restrict__ Wo, const float* __restrict__ bo, const float* __restrict__ tho,
        float* __restrict__ Xproj) {
    __shared__ __align__(16) float Wl[16][132];
    __shared__ __align__(16) float rows[16][132];
    __shared__ float bl[16];
    const int tid = threadIdx.x;
    {
        const float* Wm[4] = {Wf, Wi, Wu, Wo};
        for (int idx = tid; idx < 16 * E; idx += 256) {
            int e = idx >> 4, q = idx & 15;
            int g = q & 3, j = q >> 2;
            Wl[q][e] = Wm[g][e * 4 + j] * INV2PI;
        }
        if (tid < 16) {
            const float* bm[4] = {bf, bi, bu, bo};
            const float* tm[4] = {thf, thi, thu, tho};
            int g = tid & 3, j = tid >> 2;
            bl[tid] = (bm[g][j] + tm[g][j]) * INV2PI;
        }
    }
    const int p0 = blockIdx.x * 16;
    #pragma unroll
    for (int k = 0; k < 2; ++k) {
        int i4 = k * 256 + tid;              // float4 unit: 16 rows x 32
        int r  = i4 >> 5;
        int e4 = i4 & 31;
        const float4* rp = (const float4*)(emb + (size_t)x[p0 + r] * E);
        *(float4*)(&rows[r][e4 * 4]) = rp[e4];
    }
    __syncthreads();
    const int pl = tid >> 4, q = tid & 15;
    float acc = bl[q];
    #pragma unroll
    for (int e = 0; e < E; e += 4) {
        float4 wv = *(const float4*)(&Wl[q][e]);
        float4 rv = *(const float4*)(&rows[pl][e]);
        acc += rv.x * wv.x + rv.y * wv.y + rv.z * wv.z + rv.w * wv.w;
    }
    Xproj[(size_t)(p0 + pl) * 16 + q] = acc;
}

// ---------------------------------------------------------------------------
// k2 v5: chunked speculative scan. Block = 4 batches x ONE chunk ci (wave-
// uniform bounds). Chunk stores steps [ci*L, ci*L+L); starts at
// ts = max(0, ci*L - WARM) from zero state: contraction (f <= 0.731,
// empirical rho ~0.83) kills the initial-state error to <1e-10 within 128
// steps. Chunks 0..4 start at t=0 -> bit-exact. Step body = round-13
// VERBATIM (lane l = g*4+j layout, unified rational gate, revolutions cos,
// butterfly gate-combine; all HW-verified).
// hbuf: [B][S][4] f32.
// ---------------------------------------------------------------------------
__global__ void __launch_bounds__(64) k2_recur(
        const float* __restrict__ Xproj,
        const float* __restrict__ Wf, const float* __restrict__ Wi,
        const float* __restrict__ Wu, const float* __restrict__ Wo,
        float* __restrict__ hbuf) {
    const int lane = threadIdx.x;
    const int ci = blockIdx.x >> 4;                      // chunk 0..15
    const int b  = (blockIdx.x & 15) * 4 + (lane >> 4);  // batch
    const int l16 = lane & 15;
    const int g = l16 >> 2, j = l16 & 3;                 // gate, wire

    const int c0 = ci * CHUNK_L;                         // first stored step
    const int ts = (c0 > WARM) ? (c0 - WARM) : 0;        // start (wave-uniform)
    const int te = c0 + CHUNK_L;                         // end

    // per-lane gate weight row (revolutions), pre-permuted: slot d = hx_{(j+d)&3}
    const float* Wg = (g == 0) ? Wf : (g == 1) ? Wi : (g == 2) ? Wu : Wo;
    const float w0 = Wg[(E + ((j + 0) & 3)) * 4 + j] * INV2PI;
    const float w1 = Wg[(E + ((j + 1) & 3)) * 4 + j] * INV2PI;
    const float w2 = Wg[(E + ((j + 2) & 3)) * 4 + j] * INV2PI;
    const float w3 = Wg[(E + ((j + 3) & 3)) * 4 + j] * INV2PI;

    // z-product inclusion masks (wire j; HW-verified)
    const bool m_own = (j != 0);
    const bool m_r1  = (j == 0) || (j == 3);
    const bool m_r2  = (j != 1);
    // gate-combine masks (gate g; HW-verified round 12)
    const bool is_u  = (g == 2);
    const bool is_f  = (g == 0);
    const bool is_iu = (g == 1) || (g == 2);
    const bool is_o  = (g == 3);

    // unified rational-gate constants (u: tanh Pade[3/4]; else sigmoid form)
    const float b0 = is_u ? 0.f   : 0.5f;
    const float n0 = is_u ? 105.f : 26.25f;
    const float n1 = is_u ? 10.f  : 0.625f;
    const float d1 = is_u ? 45.f  : 11.25f;
    const float d2 = is_u ? 1.f   : 0.0625f;

    float hx0 = 0.f, hx1 = 0.f, hx2 = 0.f, hx3 = 0.f, cx = 0.f;

    const float* xp = Xproj + (size_t)b * S * 16 + (j * 4 + g);
    float* hout = hbuf + ((size_t)b * S) * 4 + j;   // 4 g-lanes write same value

    constexpr int P = 8;                   // (te-ts) % P == 0 for all chunks
    float cur[P], nxt[P];
    #pragma unroll
    for (int p = 0; p < P; ++p) cur[p] = xp[(size_t)(ts + p) * 16];

    for (int tb = ts; tb < te; tb += P) {
        #pragma unroll
        for (int p = 0; p < P; ++p) {
            int tt = tb + P + p; if (tt >= te) tt = te - 1;   // clamped tail prefetch
            nxt[p] = xp[(size_t)tt * 16];
        }
        #pragma unroll
        for (int p = 0; p < P; ++p) {
            const int t = tb + p;

            float t1 = fmaf(w1, hx1, fmaf(w0, hx0, cur[p]));
            float t2 = fmaf(w3, hx3, w2 * hx2);
            float pre = t1 + t2;

            float c = __builtin_amdgcn_cosf(pre);   // v_cos_f32: cos(2*pi*pre)

            // z-product across wires (quads, verified)
            float a1 = rotq<0x39>(c), a2 = rotq<0x4E>(c), a3 = rotq<0x93>(c);
            float z = ((m_own ? c : 1.f) * (m_r1 ? a1 : 1.f)) * ((m_r2 ? a2 : 1.f) * a3);

            // unified rational gate
            float s = z * z;
            float num = z * fmaf(n1, s, n0);
            float den = fmaf(fmaf(d2, s, d1), s, 105.f);
            float y = fmaf(num, frcp(den), b0);

            // combine across gates: direction-agnostic butterfly products
            float ef  = is_f  ? y : 1.f;    // -> product over g-lanes = f
            float eiu = is_iu ? y : 1.f;    // -> i*u
            float eo  = is_o  ? y : 1.f;    // -> o
            float pf  = ef  * rotq<0x128>(ef);   pf  = pf  * rotq<0x124>(pf);
            float piu = eiu * rotq<0x128>(eiu);  piu = piu * rotq<0x124>(piu);
            float po  = eo  * rotq<0x128>(eo);   po  = po  * rotq<0x124>(po);

            cx = fmaf(pf, cx, piu);
            float h = po * tanh_c(cx);

            if (t >= c0)                     // wave-uniform predicate, store only
                hout[(size_t)t * 4] = h;

            hx0 = h;
            hx1 = rotq<0x39>(h); hx2 = rotq<0x4E>(h); hx3 = rotq<0x93>(h);
        }
        #pragma unroll
        for (int p = 0; p < P; ++p) cur[p] = nxt[p];
    }
}

// ---------------------------------------------------------------------------
// k3: logits = h @ Wt + bt, log_softmax over 10 tags (verified rounds 7-13).
// ---------------------------------------------------------------------------
__global__ void __launch_bounds__(256) k3_head(
        const float* __restrict__ hbuf, const float* __restrict__ Wt,
        const float* __restrict__ bt, float* __restrict__ out) {
    const int pos = blockIdx.x * 256 + threadIdx.x;
    if (pos >= B * S) return;
    float4 h = ((const float4*)hbuf)[pos];
    float lo[NT];
    float m = -1e30f;
    #pragma unroll
    for (int t = 0; t < NT; ++t) {
        lo[t] = bt[t] + h.x * Wt[t] + h.y * Wt[NT + t] + h.z * Wt[2 * NT + t] + h.w * Wt[3 * NT + t];
        m = fmaxf(m, lo[t]);
    }
    float sum = 0.f;
    #pragma unroll
    for (int t = 0; t < NT; ++t) sum += __expf(lo[t] - m);
    float lse = m + __logf(sum);
    float* op = out + (size_t)pos * NT;
    #pragma unroll
    for (int t = 0; t < NT; ++t) op[t] = lo[t] - lse;
}

extern "C" void kernel_launch(void* const* d_in, const int* in_sizes, int n_in,
                              void* d_out, int out_size, void* d_ws, size_t ws_size,
                              hipStream_t stream) {
    const int*   x   = (const int*)d_in[0];
    const float* emb = (const float*)d_in[1];
    const float* Wf  = (const float*)d_in[2];
    const float* bf  = (const float*)d_in[3];
    const float* thf = (const float*)d_in[4];
    const float* Wi  = (const float*)d_in[5];
    const float* bi  = (const float*)d_in[6];
    const float* thi = (const float*)d_in[7];
    const float* Wu  = (const float*)d_in[8];
    const float* bu  = (const float*)d_in[9];
    const float* thu = (const float*)d_in[10];
    const float* Wo  = (const float*)d_in[11];
    const float* bo  = (const float*)d_in[12];
    const float* tho = (const float*)d_in[13];
    const float* Wt  = (const float*)d_in[14];
    const float* bt  = (const float*)d_in[15];
    float* out = (float*)d_out;

    // workspace: Xproj [B*S*16] f32, then hbuf [B*S*4] f32
    if (ws_size < (size_t)(B * S * 20) * sizeof(float)) return;
    float* Xproj = (float*)d_ws;
    float* hbuf  = Xproj + (size_t)B * S * 16;

    k1_xproj<<<(B * S) / 16, 256, 0, stream>>>(x, emb, Wf, bf, thf, Wi, bi, thi,
                                               Wu, bu, thu, Wo, bo, tho, Xproj);
    k2_recur<<<NCHUNK * (B / 4), 64, 0, stream>>>(Xproj, Wf, Wi, Wu, Wo, hbuf);
    k3_head<<<(B * S) / 256, 256, 0, stream>>>(hbuf, Wt, bt, out);
}